// Round 6
// baseline (10883.069 us; speedup 1.0000x reference)
//
#include <hip/hip_runtime.h>
#include <cstdint>
#include <cstddef>
#include <cfloat>

// Persistent Seq2Seq LSTM v4 (B=32,S=T=64,E=256,H=512,V=32000), fp32.
// R6 experiment: fence-free AND low-poller two-level grid barrier.
//   R4: fences + ~500 pollers  -> 50us/barrier
//   R5: no fences + 65536 pollers -> 37us/barrier
//   R6: no fences + ~320 pollers  -> ? (theory: LLC atomic-op saturation was
//       R5's cost; expect 5-10us)
// Data path identical to R5 (proven): cross-WG state via relaxed AGENT
// atomics (LLC-coherent, no fences anywhere); ordering by s_waitcnt vmcnt(0)
// before flag store. Weights LDS-resident per phase; c-state in registers.

#define NWG   256
#define NTHR  512
#define BSZ   32
#define SLEN  64
#define TLEN  64
#define EDIM  256
#define HDIM  512
#define VOUT  32000
#define FCWGS 250
#define FCR   128          // fc rows per WG
#define CHR   16           // fc rows per chunk
#define NCHK  (FCR / CHR)  // 8
#define FSTR  16           // flag stride (u32) -> one cacheline per flag

#define XS0 20                      // EDIM slice stride: 16+4
#define HSL 36                      // HDIM slice stride: 32+4
#define RS0 (16 * XS0 + 16 * HSL)   // 896 floats / cell0 row
#define RS1 (16 * HSL + 16 * HSL)   // 1152 floats / cell1 row

struct SMem {
    float w0[8 * RS0];
    float w1[8 * RS1];
    float fcc[CHR * 16 * HSL];
    float ls[FCR * 33];
    float zsh[8 * 32];
    float cmv[4 * 32];
    int   cmi[4 * 32];
    float bsum0[8], bsum1[8];
    float fcb_s[FCR];
    int   tok[BSZ];
    int   llen[BSZ];
};

// ------------------------------------------------- relaxed agent atomics ----
__device__ __forceinline__ float aload(const float* p) {
    return __hip_atomic_load(p, __ATOMIC_RELAXED, __HIP_MEMORY_SCOPE_AGENT);
}
__device__ __forceinline__ void astore(float* p, float v) {
    __hip_atomic_store(p, v, __ATOMIC_RELAXED, __HIP_MEMORY_SCOPE_AGENT);
}
__device__ __forceinline__ int aloadi(const int* p) {
    return __hip_atomic_load(p, __ATOMIC_RELAXED, __HIP_MEMORY_SCOPE_AGENT);
}
__device__ __forceinline__ void astorei(int* p, int v) {
    __hip_atomic_store(p, v, __ATOMIC_RELAXED, __HIP_MEMORY_SCOPE_AGENT);
}
__device__ __forceinline__ float2 aload2(const float* p) {
    unsigned long long u = __hip_atomic_load((const unsigned long long*)p,
                              __ATOMIC_RELAXED, __HIP_MEMORY_SCOPE_AGENT);
    union { unsigned long long u; float2 f; } c; c.u = u; return c.f;
}

// ---------------------------------------------------------- grid barrier ----
// Two-level, fence-free, low-poller:
//   arrive : thread0/WG relaxed-stores its flag (after vmcnt drain)
//   agg    : WG0 wave0 polls 256 flags (64 lanes x 4 flags) -> publish sense
//   wait   : thread0/WG polls sense; everyone else parks at s_barrier
__device__ __forceinline__ void gridbar(unsigned* flags, unsigned* sense,
                                        unsigned& epoch)
{
    asm volatile("s_waitcnt vmcnt(0)" ::: "memory");
    __syncthreads();
    epoch++;
    const int tid = threadIdx.x;
    if (tid == 0)
        __hip_atomic_store(&flags[(size_t)blockIdx.x * FSTR], epoch,
                           __ATOMIC_RELAXED, __HIP_MEMORY_SCOPE_AGENT);
    if (blockIdx.x == 0) {
        if (tid < 64) {
#pragma unroll
            for (int k = 0; k < 4; k++) {
                const size_t idx = (size_t)(tid * 4 + k) * FSTR;
                while (__hip_atomic_load(&flags[idx], __ATOMIC_RELAXED,
                                         __HIP_MEMORY_SCOPE_AGENT) < epoch)
                    __builtin_amdgcn_s_sleep(2);
            }
        }
        __syncthreads();
        if (tid == 0)
            __hip_atomic_store(sense, epoch, __ATOMIC_RELAXED,
                               __HIP_MEMORY_SCOPE_AGENT);
    }
    if (tid == 0) {
        while (__hip_atomic_load(sense, __ATOMIC_RELAXED,
                                 __HIP_MEMORY_SCOPE_AGENT) < epoch)
            __builtin_amdgcn_s_sleep(4);
    }
    __syncthreads();
}

// ------------------------------------------------------- weight staging -----
template<int KIN>
__device__ __forceinline__ void stage_w(float* dst,
        const float* __restrict__ Wih, const float* __restrict__ Whh,
        const float* __restrict__ bih, const float* __restrict__ bhh,
        float* bsum, int j0)
{
    constexpr int XC = KIN / 16;
    constexpr int XS = (KIN == 256) ? XS0 : HSL;
    constexpr int RS = (KIN == 256) ? RS0 : RS1;
    const int tid = threadIdx.x;
    constexpr int nf4x = KIN / 4;
    for (int tt = tid; tt < 8 * nf4x; tt += NTHR) {
        int r = tt / nf4x, k = (tt % nf4x) * 4;
        int row = (r >> 1) * HDIM + j0 + (r & 1);
        float4 v = *(const float4*)(Wih + (size_t)row * KIN + k);
        *(float4*)(dst + r * RS + (k / XC) * XS + (k % XC)) = v;
    }
    for (int tt = tid; tt < 8 * 128; tt += NTHR) {
        int r = tt >> 7, k = (tt & 127) * 4;
        int row = (r >> 1) * HDIM + j0 + (r & 1);
        float4 v = *(const float4*)(Whh + (size_t)row * HDIM + k);
        *(float4*)(dst + r * RS + 16 * XS + (k >> 5) * HSL + (k & 31)) = v;
    }
    if (tid < 8) {
        int row = (tid >> 1) * HDIM + j0 + (tid & 1);
        bsum[tid] = bih[row] + bhh[row];
    }
}

// ------------------------------------------------------------- LSTM cell ----
// lane = (bl:4 x kq:16); 8 z-rows per WG (2 j x 4 gates).
// AX: x is cross-WG state (h0) -> atomic loads; else plain (emb rows).
template<int KIN, bool AX>
__device__ __forceinline__ void cell_run(SMem& sm, const float* __restrict__ w,
        const float* bsum, const float* __restrict__ xrow,
        const float* __restrict__ hin, float* __restrict__ hout,
        float& creg, bool domask, int s, int j0)
{
    constexpr int XC = KIN / 16;
    constexpr int XS = (KIN == 256) ? XS0 : HSL;
    constexpr int RS = (KIN == 256) ? RS0 : RS1;
    const int tid = threadIdx.x;
    const int wave = tid >> 6, lane = tid & 63, kq = lane & 15, bl = lane >> 4;
    const int b = wave * 4 + bl;

    float xv[XC];
    if (AX) {
#pragma unroll
        for (int i = 0; i < XC / 2; i++) {
            float2 t = aload2(xrow + kq * XC + i * 2);
            xv[i * 2] = t.x; xv[i * 2 + 1] = t.y;
        }
    } else {
#pragma unroll
        for (int i = 0; i < XC / 4; i++) {
            float4 t = *(const float4*)(xrow + kq * XC + i * 4);
            xv[i * 4] = t.x; xv[i * 4 + 1] = t.y; xv[i * 4 + 2] = t.z; xv[i * 4 + 3] = t.w;
        }
    }
    float hv[32];
    {
        const float* hp = hin + (size_t)b * HDIM + kq * 32;
#pragma unroll
        for (int i = 0; i < 16; i++) {
            float2 t = aload2(hp + i * 2);
            hv[i * 2] = t.x; hv[i * 2 + 1] = t.y;
        }
    }

    __syncthreads();   // zsh free (previous consumers done)
#pragma unroll
    for (int r = 0; r < 8; r++) {
        float acc = 0.f;
        const float* wx = w + r * RS + kq * XS;
#pragma unroll
        for (int i = 0; i < XC / 4; i++) {
            float4 t4 = *(const float4*)(wx + i * 4);
            acc += t4.x * xv[i*4] + t4.y * xv[i*4+1] + t4.z * xv[i*4+2] + t4.w * xv[i*4+3];
        }
        const float* wh = w + r * RS + 16 * XS + kq * HSL;
#pragma unroll
        for (int i = 0; i < 8; i++) {
            float4 t4 = *(const float4*)(wh + i * 4);
            acc += t4.x * hv[i*4] + t4.y * hv[i*4+1] + t4.z * hv[i*4+2] + t4.w * hv[i*4+3];
        }
        acc += __shfl_xor(acc, 1);
        acc += __shfl_xor(acc, 2);
        acc += __shfl_xor(acc, 4);
        acc += __shfl_xor(acc, 8);
        if (kq == 0) sm.zsh[r * 32 + b] = acc + bsum[r];
    }
    __syncthreads();
    if (tid < 64) {
        int jl = tid >> 5, bb = tid & 31;
        float zi = sm.zsh[(0 + jl) * 32 + bb];
        float zf = sm.zsh[(2 + jl) * 32 + bb];
        float zg = sm.zsh[(4 + jl) * 32 + bb];
        float zo = sm.zsh[(6 + jl) * 32 + bb];
        float iv = 1.f / (1.f + expf(-zi));
        float fv = 1.f / (1.f + expf(-zf));
        float gv = tanhf(zg);
        float ov = 1.f / (1.f + expf(-zo));
        float cold = creg;
        float c2 = fv * cold + iv * gv;
        float h2 = ov * tanhf(c2);
        size_t off = (size_t)bb * HDIM + j0 + jl;
        if (domask) {
            bool m = s < sm.llen[bb];
            if (!m) { h2 = aload(hin + off); c2 = cold; }
        }
        astore(hout + off, h2);
        creg = c2;
    }
}

// --------------------------------------------------------------------- fc ---
__device__ __forceinline__ void fc_run(SMem& sm, const float* __restrict__ h,
        const float* __restrict__ fcW, float* __restrict__ out, int t, int g,
        float* __restrict__ cand_val, int* __restrict__ cand_idx)
{
    const int tid = threadIdx.x;
    const int wave = tid >> 6, lane = tid & 63, kq = lane & 15, bg = lane >> 4;
    const int bh = wave & 1, qr = wave >> 1;
    const int bb = bh * 16 + bg * 4;
    const size_t v0 = (size_t)g * FCR;

    float hrs[4][32];
#pragma unroll
    for (int j = 0; j < 4; j++) {
        const float* hp = h + (size_t)(bb + j) * HDIM + kq * 32;
#pragma unroll
        for (int i = 0; i < 16; i++) {
            float2 u = aload2(hp + i * 2);
            hrs[j][i * 2] = u.x; hrs[j][i * 2 + 1] = u.y;
        }
    }

    float4 pf[4];
#pragma unroll
    for (int j = 0; j < 4; j++) {
        int tt = tid + j * NTHR;
        int r = tt >> 7, k = (tt & 127) * 4;
        pf[j] = *(const float4*)(fcW + (v0 + r) * HDIM + k);
    }

    float vmax[4]; int vidx[4];
#pragma unroll
    for (int j = 0; j < 4; j++) { vmax[j] = -FLT_MAX; vidx[j] = 0; }

    for (int c = 0; c < NCHK; c++) {
        __syncthreads();
#pragma unroll
        for (int j = 0; j < 4; j++) {
            int tt = tid + j * NTHR;
            int r = tt >> 7, k = (tt & 127) * 4;
            *(float4*)(sm.fcc + r * (16 * HSL) + (k >> 5) * HSL + (k & 31)) = pf[j];
        }
        if (c + 1 < NCHK) {
#pragma unroll
            for (int j = 0; j < 4; j++) {
                int tt = tid + j * NTHR;
                int r = tt >> 7, k = (tt & 127) * 4;
                pf[j] = *(const float4*)(fcW + (v0 + (c + 1) * CHR + r) * HDIM + k);
            }
        }
        __syncthreads();
#pragma unroll
        for (int r = 0; r < 4; r++) {
            int rc = qr * 4 + r;
            int rr = c * CHR + rc;
            const float* wp = sm.fcc + rc * (16 * HSL) + kq * HSL;
            float a0 = 0.f, a1 = 0.f, a2 = 0.f, a3 = 0.f;
#pragma unroll
            for (int i = 0; i < 8; i++) {
                float4 w4 = *(const float4*)(wp + i * 4);
                a0 += w4.x * hrs[0][i*4] + w4.y * hrs[0][i*4+1] + w4.z * hrs[0][i*4+2] + w4.w * hrs[0][i*4+3];
                a1 += w4.x * hrs[1][i*4] + w4.y * hrs[1][i*4+1] + w4.z * hrs[1][i*4+2] + w4.w * hrs[1][i*4+3];
                a2 += w4.x * hrs[2][i*4] + w4.y * hrs[2][i*4+1] + w4.z * hrs[2][i*4+2] + w4.w * hrs[2][i*4+3];
                a3 += w4.x * hrs[3][i*4] + w4.y * hrs[3][i*4+1] + w4.z * hrs[3][i*4+2] + w4.w * hrs[3][i*4+3];
            }
#pragma unroll
            for (int m = 1; m < 16; m <<= 1) {
                a0 += __shfl_xor(a0, m);
                a1 += __shfl_xor(a1, m);
                a2 += __shfl_xor(a2, m);
                a3 += __shfl_xor(a3, m);
            }
            if (kq == 0) {
                float bias = sm.fcb_s[rr];
                float z[4] = { a0 + bias, a1 + bias, a2 + bias, a3 + bias };
#pragma unroll
                for (int j = 0; j < 4; j++) {
                    sm.ls[rr * 33 + bb + j] = z[j];
                    if (z[j] > vmax[j]) { vmax[j] = z[j]; vidx[j] = (int)(v0 + rr); }
                }
            }
        }
    }
    if (kq == 0) {
#pragma unroll
        for (int j = 0; j < 4; j++) {
            sm.cmv[qr * 32 + bb + j] = vmax[j];
            sm.cmi[qr * 32 + bb + j] = vidx[j];
        }
    }
    __syncthreads();
    if (tid < 32) {
        float bv = sm.cmv[tid]; int bi = sm.cmi[tid];
#pragma unroll
        for (int q = 1; q < 4; q++) {
            float v = sm.cmv[q * 32 + tid]; int ix = sm.cmi[q * 32 + tid];
            if (v > bv || (v == bv && ix < bi)) { bv = v; bi = ix; }
        }
        astore(&cand_val[(size_t)tid * NWG + g], bv);
        astorei(&cand_idx[(size_t)tid * NWG + g], bi);
    }
    // logits: plain stores (write-only; no fences anywhere -> dirty L2 free)
    {
        int b2 = tid >> 4, q16 = tid & 15;
        float* op = out + ((size_t)b2 * TLEN + t) * VOUT + v0 + q16 * 8;
        float4 u0, u1;
        u0.x = sm.ls[(q16 * 8 + 0) * 33 + b2];
        u0.y = sm.ls[(q16 * 8 + 1) * 33 + b2];
        u0.z = sm.ls[(q16 * 8 + 2) * 33 + b2];
        u0.w = sm.ls[(q16 * 8 + 3) * 33 + b2];
        u1.x = sm.ls[(q16 * 8 + 4) * 33 + b2];
        u1.y = sm.ls[(q16 * 8 + 5) * 33 + b2];
        u1.z = sm.ls[(q16 * 8 + 6) * 33 + b2];
        u1.w = sm.ls[(q16 * 8 + 7) * 33 + b2];
        *(float4*)op = u0;
        *(float4*)(op + 4) = u1;
    }
}

// --------------------------------------------------------- main persistent --
__global__ __launch_bounds__(NTHR, 2)
void seq2seq_persist(
    const int* __restrict__ inputs, const int* __restrict__ lens,
    const float* __restrict__ enc_emb, const float* __restrict__ dec_emb,
    const float* __restrict__ eW0ih, const float* __restrict__ eW0hh,
    const float* __restrict__ eB0ih, const float* __restrict__ eB0hh,
    const float* __restrict__ eW1ih, const float* __restrict__ eW1hh,
    const float* __restrict__ eB1ih, const float* __restrict__ eB1hh,
    const float* __restrict__ dW0ih, const float* __restrict__ dW0hh,
    const float* __restrict__ dB0ih, const float* __restrict__ dB0hh,
    const float* __restrict__ dW1ih, const float* __restrict__ dW1hh,
    const float* __restrict__ dB1ih, const float* __restrict__ dB1hh,
    const float* __restrict__ fcW, const float* __restrict__ fcb,
    float* __restrict__ out,
    float* h0a, float* h0b, float* h1a, float* h1b,
    float* cand_val, int* cand_idx, unsigned* flags, unsigned* sense)
{
    __shared__ SMem sm;
    const int g = blockIdx.x;
    const int tid = threadIdx.x;
    const int j0 = g * 2;
    unsigned epoch = 0;

    const int wave = tid >> 6, lane = tid & 63, bl = lane >> 4;
    const int b = wave * 4 + bl;

    float* h0[2] = { h0a, h0b };
    float* h1[2] = { h1a, h1b };

    // zero initial h state (atomic stores: readers use atomic loads)
    if (tid < 64) {
        astore(&h0a[g * 64 + tid], 0.f);
        astore(&h1a[g * 64 + tid], 0.f);
    }
    stage_w<EDIM>(sm.w0, eW0ih, eW0hh, eB0ih, eB0hh, sm.bsum0, j0);
    stage_w<HDIM>(sm.w1, eW1ih, eW1hh, eB1ih, eB1hh, sm.bsum1, j0);
    if (tid < BSZ) sm.llen[tid] = lens[tid];
    float c0r = 0.f, c1r = 0.f;
    gridbar(flags, sense, epoch);

    // ---- encoder: pipelined, 1 barrier/phase ----
    for (int s = 0; s <= SLEN; ++s) {
        int p = s & 1;
        if (s < SLEN) {
            const float* x0 = enc_emb + (size_t)inputs[b * SLEN + s] * EDIM;
            cell_run<EDIM, false>(sm, sm.w0, sm.bsum0, x0, h0[p], h0[p ^ 1], c0r,
                                  true, s, j0);
        }
        if (s >= 1) {
            int q = (s - 1) & 1;
            cell_run<HDIM, true>(sm, sm.w1, sm.bsum1, h0[p] + (size_t)b * HDIM,
                                 h1[q], h1[q ^ 1], c1r, true, s - 1, j0);
        }
        gridbar(flags, sense, epoch);
    }
    // finals in h0[0], h1[0]

    // ---- decoder setup ----
    stage_w<EDIM>(sm.w0, dW0ih, dW0hh, dB0ih, dB0hh, sm.bsum0, j0);
    stage_w<HDIM>(sm.w1, dW1ih, dW1hh, dB1ih, dB1hh, sm.bsum1, j0);
    if (g < FCWGS)
        for (int i = tid; i < FCR; i += NTHR) sm.fcb_s[i] = fcb[g * FCR + i];
    c0r = 0.f; c1r = 0.f;
    __syncthreads();

    // ---- decoder: 3 barriers/step ----
    for (int t = 0; t < TLEN; ++t) {
        int p = t & 1;
        if (t == 0) {
            if (tid < BSZ) sm.tok[tid] = 1;
        } else if (tid < 256) {
            int bq = tid >> 3, q = tid & 7;
            float bv = -FLT_MAX; int bi = 0x7fffffff;
            for (int gg = q; gg < FCWGS; gg += 8) {
                float v = aload(&cand_val[(size_t)bq * NWG + gg]);
                int  ix = aloadi(&cand_idx[(size_t)bq * NWG + gg]);
                if (v > bv || (v == bv && ix < bi)) { bv = v; bi = ix; }
            }
#pragma unroll
            for (int m = 1; m < 8; m <<= 1) {
                float ov = __shfl_xor(bv, m); int oi = __shfl_xor(bi, m);
                if (ov > bv || (ov == bv && oi < bi)) { bv = ov; bi = oi; }
            }
            if (q == 0) sm.tok[bq] = bi;
        }
        __syncthreads();
        const float* x0 = dec_emb + (size_t)sm.tok[b] * EDIM;
        cell_run<EDIM, false>(sm, sm.w0, sm.bsum0, x0, h0[p], h0[p ^ 1], c0r,
                              false, 0, j0);
        gridbar(flags, sense, epoch);
        cell_run<HDIM, true>(sm, sm.w1, sm.bsum1, h0[p ^ 1] + (size_t)b * HDIM,
                             h1[p], h1[p ^ 1], c1r, false, 0, j0);
        gridbar(flags, sense, epoch);
        if (g < FCWGS)
            fc_run(sm, h1[p ^ 1], fcW, out, t, g, cand_val, cand_idx);
        gridbar(flags, sense, epoch);
    }
}

// ------------------------------------------------------------------- init ---
__global__ void initk(unsigned* flags)
{
    int i = blockIdx.x * 256 + threadIdx.x;
    if (i < NWG * FSTR + 16) flags[i] = 0u;   // flags + sense line
}

// ----------------------------------------------------------------- driver ---
extern "C" void kernel_launch(void* const* d_in, const int* in_sizes, int n_in,
                              void* d_out, int out_size, void* d_ws, size_t ws_size,
                              hipStream_t stream)
{
    const int*   inputs  = (const int*)d_in[0];
    const int*   lens    = (const int*)d_in[3];
    const float* enc_emb = (const float*)d_in[4];
    const float* dec_emb = (const float*)d_in[5];
    const float* W[16];
    for (int i = 0; i < 16; i++) W[i] = (const float*)d_in[6 + i];
    const float* fcW = (const float*)d_in[22];
    const float* fcb = (const float*)d_in[23];
    float* out = (float*)d_out;

    float* ws = (float*)d_ws;
    float* h0a = ws;
    float* h0b = ws + 16384;
    float* h1a = ws + 32768;
    float* h1b = ws + 49152;
    float* cand_val = ws + 65536;                       // 32*256
    int*   cand_idx = (int*)(ws + 65536 + 8192);        // 32*256
    unsigned* flags = (unsigned*)(ws + 65536 + 16384);  // 256*16 + sense

    initk<<<17, 256, 0, stream>>>(flags);
    seq2seq_persist<<<NWG, NTHR, 0, stream>>>(
        inputs, lens, enc_emb, dec_emb,
        W[0], W[1], W[2], W[3], W[4], W[5], W[6], W[7],
        W[8], W[9], W[10], W[11], W[12], W[13], W[14], W[15],
        fcW, fcb, out,
        h0a, h0b, h1a, h1b, cand_val, cand_idx, flags, flags + NWG * FSTR);
}

// Round 7
// 7538.934 us; speedup vs baseline: 1.4436x; 1.4436x over previous
//
#include <hip/hip_runtime.h>
#include <cstdint>
#include <cstddef>
#include <cfloat>

// Persistent Seq2Seq LSTM v5 (B=32,S=T=64,E=256,H=512,V=32000), fp32.
// R7 experiment: coalesced cooperative staging of ALL cross-WG data.
//   R4: fences                -> 50us/phase
//   R5/R6: fence-free barrier -> 37us/phase regardless of poller count
//   Theory: scattered 8B agent-atomic loads (2M-8M LLC transactions/phase)
//   are the cost. Fix: one coalesced atomic sweep -> LDS, then ds_read_b128.
// Barrier identical to R6 (isolates the data-path change).

#define NWG   256
#define NTHR  512
#define BSZ   32
#define SLEN  64
#define TLEN  64
#define EDIM  256
#define HDIM  512
#define VOUT  32000
#define FCWGS 250
#define FCR   128          // fc rows per WG
#define CHR   16           // fc rows per chunk
#define NCHK  (FCR / CHR)  // 8
#define FSTR  16           // flag stride (u32)

#define XS0 20                      // EDIM slice stride
#define HSL 36                      // HDIM slice stride
#define RS0 (16 * XS0 + 16 * HSL)   // 896 floats / cell0 row
#define RS1 (16 * HSL + 16 * HSL)   // 1152 floats / cell1 row
#define HB  576                     // staged-h per-b stride (16 chunks * 36)

struct SMem {
    float w0[8 * RS0];          // 28.7 KB
    float w1[8 * RS1];          // 36.9 KB
    float reg[18432];           // 73.7 KB: h-stage (32*576) | cand | fcc+ls
    float zsh0[8 * 32], zsh1[8 * 32];
    float cmv[4 * 32];
    int   cmi[4 * 32];
    float bsum0[8], bsum1[8];
    float fcb_s[FCR];
    int   tok[BSZ];
    int   llen[BSZ];
};                              // ~140 KB -> 1 WG/CU

// ------------------------------------------------- relaxed agent atomics ----
__device__ __forceinline__ float aload(const float* p) {
    return __hip_atomic_load(p, __ATOMIC_RELAXED, __HIP_MEMORY_SCOPE_AGENT);
}
__device__ __forceinline__ void astore(float* p, float v) {
    __hip_atomic_store(p, v, __ATOMIC_RELAXED, __HIP_MEMORY_SCOPE_AGENT);
}
__device__ __forceinline__ void astorei(int* p, int v) {
    __hip_atomic_store(p, v, __ATOMIC_RELAXED, __HIP_MEMORY_SCOPE_AGENT);
}
__device__ __forceinline__ float2 aload2(const float* p) {
    unsigned long long u = __hip_atomic_load((const unsigned long long*)p,
                              __ATOMIC_RELAXED, __HIP_MEMORY_SCOPE_AGENT);
    union { unsigned long long u; float2 f; } c; c.u = u; return c.f;
}

// ---------------------------------------------------------- grid barrier ----
// Two-level, fence-free (identical to R6).
__device__ __forceinline__ void gridbar(unsigned* flags, unsigned* sense,
                                        unsigned& epoch)
{
    asm volatile("s_waitcnt vmcnt(0)" ::: "memory");
    __syncthreads();
    epoch++;
    const int tid = threadIdx.x;
    if (tid == 0)
        __hip_atomic_store(&flags[(size_t)blockIdx.x * FSTR], epoch,
                           __ATOMIC_RELAXED, __HIP_MEMORY_SCOPE_AGENT);
    if (blockIdx.x == 0) {
        if (tid < 64) {
#pragma unroll
            for (int k = 0; k < 4; k++) {
                const size_t idx = (size_t)(tid * 4 + k) * FSTR;
                while (__hip_atomic_load(&flags[idx], __ATOMIC_RELAXED,
                                         __HIP_MEMORY_SCOPE_AGENT) < epoch)
                    __builtin_amdgcn_s_sleep(2);
            }
        }
        __syncthreads();
        if (tid == 0)
            __hip_atomic_store(sense, epoch, __ATOMIC_RELAXED,
                               __HIP_MEMORY_SCOPE_AGENT);
    }
    if (tid == 0) {
        while (__hip_atomic_load(sense, __ATOMIC_RELAXED,
                                 __HIP_MEMORY_SCOPE_AGENT) < epoch)
            __builtin_amdgcn_s_sleep(4);
    }
    __syncthreads();
}

// ------------------------------------------------- coalesced h staging ------
// 64KB buffer hg -> LDS [b][chunk-of-32 padded to 36], b-stride 576.
// thread t loads 16 consecutive-8B pieces (perfect line coalescing).
__device__ __forceinline__ void stage_h(float* reg, const float* __restrict__ hg)
{
    const int t = threadIdx.x;
#pragma unroll
    for (int i = 0; i < 16; i++) {
        int f = i * 1024 + t * 2;
        float2 v = aload2(hg + f);
        int b = f >> 9, j = f & 511;            // j even -> both in same chunk
        int a = b * HB + (j >> 5) * 36 + (j & 31);
        *(float2*)(&reg[a]) = v;
    }
}
__device__ __forceinline__ void read_slice32(const float* reg, int b, int kq,
                                             float* dst)
{
#pragma unroll
    for (int i = 0; i < 8; i++) {
        float4 v = *(const float4*)(reg + b * HB + kq * 36 + i * 4);
        dst[i * 4 + 0] = v.x; dst[i * 4 + 1] = v.y;
        dst[i * 4 + 2] = v.z; dst[i * 4 + 3] = v.w;
    }
}

// ------------------------------------------------------- weight staging -----
template<int KIN>
__device__ __forceinline__ void stage_w(float* dst,
        const float* __restrict__ Wih, const float* __restrict__ Whh,
        const float* __restrict__ bih, const float* __restrict__ bhh,
        float* bsum, int j0)
{
    constexpr int XC = KIN / 16;
    constexpr int XS = (KIN == 256) ? XS0 : HSL;
    constexpr int RS = (KIN == 256) ? RS0 : RS1;
    const int tid = threadIdx.x;
    constexpr int nf4x = KIN / 4;
    for (int tt = tid; tt < 8 * nf4x; tt += NTHR) {
        int r = tt / nf4x, k = (tt % nf4x) * 4;
        int row = (r >> 1) * HDIM + j0 + (r & 1);
        float4 v = *(const float4*)(Wih + (size_t)row * KIN + k);
        *(float4*)(dst + r * RS + (k / XC) * XS + (k % XC)) = v;
    }
    for (int tt = tid; tt < 8 * 128; tt += NTHR) {
        int r = tt >> 7, k = (tt & 127) * 4;
        int row = (r >> 1) * HDIM + j0 + (r & 1);
        float4 v = *(const float4*)(Whh + (size_t)row * HDIM + k);
        *(float4*)(dst + r * RS + 16 * XS + (k >> 5) * HSL + (k & 31)) = v;
    }
    if (tid < 8) {
        int row = (tid >> 1) * HDIM + j0 + (tid & 1);
        bsum[tid] = bih[row] + bhh[row];
    }
}

// ------------------------------------------------------------- LSTM cell ----
// xv/hv pre-loaded in registers by caller. Masked h_old read from staged LDS
// (sm.reg must still hold this cell's hin buffer when the gate section runs).
template<int KIN>
__device__ __forceinline__ void cell_compute(SMem& sm, const float* __restrict__ w,
        const float* bsum, const float* xv, const float* hv,
        float* __restrict__ hout, float& creg, bool domask, int s, int j0,
        float* zsh)
{
    constexpr int XC = KIN / 16;
    constexpr int XS = (KIN == 256) ? XS0 : HSL;
    constexpr int RS = (KIN == 256) ? RS0 : RS1;
    const int tid = threadIdx.x;
    const int wave = tid >> 6, lane = tid & 63, kq = lane & 15, bl = lane >> 4;
    const int b = wave * 4 + bl;

#pragma unroll
    for (int r = 0; r < 8; r++) {
        float acc = 0.f;
        const float* wx = w + r * RS + kq * XS;
#pragma unroll
        for (int i = 0; i < XC / 4; i++) {
            float4 t4 = *(const float4*)(wx + i * 4);
            acc += t4.x * xv[i*4] + t4.y * xv[i*4+1] + t4.z * xv[i*4+2] + t4.w * xv[i*4+3];
        }
        const float* wh = w + r * RS + 16 * XS + kq * HSL;
#pragma unroll
        for (int i = 0; i < 8; i++) {
            float4 t4 = *(const float4*)(wh + i * 4);
            acc += t4.x * hv[i*4] + t4.y * hv[i*4+1] + t4.z * hv[i*4+2] + t4.w * hv[i*4+3];
        }
        acc += __shfl_xor(acc, 1);
        acc += __shfl_xor(acc, 2);
        acc += __shfl_xor(acc, 4);
        acc += __shfl_xor(acc, 8);
        if (kq == 0) zsh[r * 32 + b] = acc + bsum[r];
    }
    __syncthreads();
    if (tid < 64) {
        int jl = tid >> 5, bb = tid & 31;
        float zi = zsh[(0 + jl) * 32 + bb];
        float zf = zsh[(2 + jl) * 32 + bb];
        float zg = zsh[(4 + jl) * 32 + bb];
        float zo = zsh[(6 + jl) * 32 + bb];
        float iv = 1.f / (1.f + expf(-zi));
        float fv = 1.f / (1.f + expf(-zf));
        float gv = tanhf(zg);
        float ov = 1.f / (1.f + expf(-zo));
        float cold = creg;
        float c2 = fv * cold + iv * gv;
        float h2 = ov * tanhf(c2);
        int j = j0 + jl;
        if (domask) {
            bool m = s < sm.llen[bb];
            if (!m) {
                h2 = sm.reg[bb * HB + (j >> 5) * 36 + (j & 31)];  // staged hin
                c2 = cold;
            }
        }
        astore(hout + (size_t)bb * HDIM + j, h2);
        creg = c2;
    }
}

// --------------------------------------------------------------------- fc ---
__device__ __forceinline__ void fc_run(SMem& sm, const float* __restrict__ h1g,
        const float* __restrict__ fcW, float* __restrict__ out, int t, int g,
        float* __restrict__ cand_val, int* __restrict__ cand_idx)
{
    const int tid = threadIdx.x;
    const int wave = tid >> 6, lane = tid & 63, kq = lane & 15, bg = lane >> 4;
    const int bh = wave & 1, qr = wave >> 1;
    const int bb = bh * 16 + bg * 4;
    const size_t v0 = (size_t)g * FCR;

    // prefetch chunk 0 of fcW (plain cached; overlaps with h staging)
    float4 pf[4];
#pragma unroll
    for (int j = 0; j < 4; j++) {
        int tt = tid + j * NTHR;
        int r = tt >> 7, k = (tt & 127) * 4;
        pf[j] = *(const float4*)(fcW + (v0 + r) * HDIM + k);
    }

    stage_h(sm.reg, h1g);
    __syncthreads();
    float hrs[4][32];
#pragma unroll
    for (int j = 0; j < 4; j++)
        read_slice32(sm.reg, bb + j, kq, hrs[j]);
    __syncthreads();                // reg region now free for fcc/ls

    float* fcc = sm.reg;            // 16 rows * 576 = 9216 floats
    float* ls  = sm.reg + 9216;     // 128 * 33 = 4224 floats

    float vmax[4]; int vidx[4];
#pragma unroll
    for (int j = 0; j < 4; j++) { vmax[j] = -FLT_MAX; vidx[j] = 0; }

    for (int c = 0; c < NCHK; c++) {
        __syncthreads();            // previous chunk fully consumed
#pragma unroll
        for (int j = 0; j < 4; j++) {
            int tt = tid + j * NTHR;
            int r = tt >> 7, k = (tt & 127) * 4;
            *(float4*)(fcc + r * (16 * HSL) + (k >> 5) * HSL + (k & 31)) = pf[j];
        }
        if (c + 1 < NCHK) {
#pragma unroll
            for (int j = 0; j < 4; j++) {
                int tt = tid + j * NTHR;
                int r = tt >> 7, k = (tt & 127) * 4;
                pf[j] = *(const float4*)(fcW + (v0 + (c + 1) * CHR + r) * HDIM + k);
            }
        }
        __syncthreads();
#pragma unroll
        for (int r = 0; r < 4; r++) {
            int rc = qr * 4 + r;
            int rr = c * CHR + rc;
            const float* wp = fcc + rc * (16 * HSL) + kq * HSL;
            float a0 = 0.f, a1 = 0.f, a2 = 0.f, a3 = 0.f;
#pragma unroll
            for (int i = 0; i < 8; i++) {
                float4 w4 = *(const float4*)(wp + i * 4);
                a0 += w4.x * hrs[0][i*4] + w4.y * hrs[0][i*4+1] + w4.z * hrs[0][i*4+2] + w4.w * hrs[0][i*4+3];
                a1 += w4.x * hrs[1][i*4] + w4.y * hrs[1][i*4+1] + w4.z * hrs[1][i*4+2] + w4.w * hrs[1][i*4+3];
                a2 += w4.x * hrs[2][i*4] + w4.y * hrs[2][i*4+1] + w4.z * hrs[2][i*4+2] + w4.w * hrs[2][i*4+3];
                a3 += w4.x * hrs[3][i*4] + w4.y * hrs[3][i*4+1] + w4.z * hrs[3][i*4+2] + w4.w * hrs[3][i*4+3];
            }
#pragma unroll
            for (int m = 1; m < 16; m <<= 1) {
                a0 += __shfl_xor(a0, m);
                a1 += __shfl_xor(a1, m);
                a2 += __shfl_xor(a2, m);
                a3 += __shfl_xor(a3, m);
            }
            if (kq == 0) {
                float bias = sm.fcb_s[rr];
                float z[4] = { a0 + bias, a1 + bias, a2 + bias, a3 + bias };
#pragma unroll
                for (int j = 0; j < 4; j++) {
                    ls[rr * 33 + bb + j] = z[j];
                    if (z[j] > vmax[j]) { vmax[j] = z[j]; vidx[j] = (int)(v0 + rr); }
                }
            }
        }
    }
    if (kq == 0) {
#pragma unroll
        for (int j = 0; j < 4; j++) {
            sm.cmv[qr * 32 + bb + j] = vmax[j];
            sm.cmi[qr * 32 + bb + j] = vidx[j];
        }
    }
    __syncthreads();
    if (tid < 32) {
        float bv = sm.cmv[tid]; int bi = sm.cmi[tid];
#pragma unroll
        for (int q = 1; q < 4; q++) {
            float v = sm.cmv[q * 32 + tid]; int ix = sm.cmi[q * 32 + tid];
            if (v > bv || (v == bv && ix < bi)) { bv = v; bi = ix; }
        }
        astore(&cand_val[(size_t)tid * NWG + g], bv);
        astorei(&cand_idx[(size_t)tid * NWG + g], bi);
    }
    // logits: plain stores (write-only)
    {
        int b2 = tid >> 4, q16 = tid & 15;
        float* op = out + ((size_t)b2 * TLEN + t) * VOUT + v0 + q16 * 8;
        float4 u0, u1;
        u0.x = ls[(q16 * 8 + 0) * 33 + b2];
        u0.y = ls[(q16 * 8 + 1) * 33 + b2];
        u0.z = ls[(q16 * 8 + 2) * 33 + b2];
        u0.w = ls[(q16 * 8 + 3) * 33 + b2];
        u1.x = ls[(q16 * 8 + 4) * 33 + b2];
        u1.y = ls[(q16 * 8 + 5) * 33 + b2];
        u1.z = ls[(q16 * 8 + 6) * 33 + b2];
        u1.w = ls[(q16 * 8 + 7) * 33 + b2];
        *(float4*)op = u0;
        *(float4*)(op + 4) = u1;
    }
}

// --------------------------------------------------------- main persistent --
__global__ __launch_bounds__(NTHR, 2)
void seq2seq_persist(
    const int* __restrict__ inputs, const int* __restrict__ lens,
    const float* __restrict__ enc_emb, const float* __restrict__ dec_emb,
    const float* __restrict__ eW0ih, const float* __restrict__ eW0hh,
    const float* __restrict__ eB0ih, const float* __restrict__ eB0hh,
    const float* __restrict__ eW1ih, const float* __restrict__ eW1hh,
    const float* __restrict__ eB1ih, const float* __restrict__ eB1hh,
    const float* __restrict__ dW0ih, const float* __restrict__ dW0hh,
    const float* __restrict__ dB0ih, const float* __restrict__ dB0hh,
    const float* __restrict__ dW1ih, const float* __restrict__ dW1hh,
    const float* __restrict__ dB1ih, const float* __restrict__ dB1hh,
    const float* __restrict__ fcW, const float* __restrict__ fcb,
    float* __restrict__ out,
    float* h0a, float* h0b, float* h1a, float* h1b,
    float* cand_val, int* cand_idx, unsigned* flags, unsigned* sense)
{
    __shared__ SMem sm;
    const int g = blockIdx.x;
    const int tid = threadIdx.x;
    const int j0 = g * 2;
    unsigned epoch = 0;

    const int wave = tid >> 6, lane = tid & 63, kq = lane & 15, bl = lane >> 4;
    const int b = wave * 4 + bl;

    float* h0[2] = { h0a, h0b };
    float* h1[2] = { h1a, h1b };

    if (tid < 64) {
        astore(&h0a[g * 64 + tid], 0.f);
        astore(&h1a[g * 64 + tid], 0.f);
    }
    stage_w<EDIM>(sm.w0, eW0ih, eW0hh, eB0ih, eB0hh, sm.bsum0, j0);
    stage_w<HDIM>(sm.w1, eW1ih, eW1hh, eB1ih, eB1hh, sm.bsum1, j0);
    if (tid < BSZ) sm.llen[tid] = lens[tid];
    float c0r = 0.f, c1r = 0.f;
    gridbar(flags, sense, epoch);

    // ---- encoder: pipelined (cell0(s) || cell1(s-1)), 1 barrier/phase ----
    for (int s = 0; s <= SLEN; ++s) {
        int p = s & 1;
        stage_h(sm.reg, h0[p]);                 // read by cell0 (hin) + cell1 (x)
        __syncthreads();
        float xv0[16], hv0[32], xv1[32];
        if (s < SLEN) {
            int tokv = inputs[b * SLEN + s];
            const float* x0 = enc_emb + (size_t)tokv * EDIM;
#pragma unroll
            for (int i = 0; i < 4; i++) {
                float4 v = *(const float4*)(x0 + kq * 16 + i * 4);
                xv0[i*4] = v.x; xv0[i*4+1] = v.y; xv0[i*4+2] = v.z; xv0[i*4+3] = v.w;
            }
            read_slice32(sm.reg, b, kq, hv0);
        }
        if (s >= 1) read_slice32(sm.reg, b, kq, xv1);
        if (s < SLEN)
            cell_compute<EDIM>(sm, sm.w0, sm.bsum0, xv0, hv0, h0[p ^ 1], c0r,
                               true, s, j0, sm.zsh0);
        __syncthreads();
        if (s >= 1) {
            int q = (s - 1) & 1;
            stage_h(sm.reg, h1[q]);
            __syncthreads();
            float hv1[32];
            read_slice32(sm.reg, b, kq, hv1);
            cell_compute<HDIM>(sm, sm.w1, sm.bsum1, xv1, hv1, h1[q ^ 1], c1r,
                               true, s - 1, j0, sm.zsh1);
        }
        gridbar(flags, sense, epoch);
    }
    // finals in h0[0], h1[0]

    // ---- decoder setup ----
    stage_w<EDIM>(sm.w0, dW0ih, dW0hh, dB0ih, dB0hh, sm.bsum0, j0);
    stage_w<HDIM>(sm.w1, dW1ih, dW1hh, dB1ih, dB1hh, sm.bsum1, j0);
    if (g < FCWGS)
        for (int i = tid; i < FCR; i += NTHR) sm.fcb_s[i] = fcb[g * FCR + i];
    c0r = 0.f; c1r = 0.f;
    __syncthreads();

    // ---- decoder: 3 barriers/step (last step: 2) ----
    for (int t = 0; t < TLEN; ++t) {
        int p = t & 1;
        if (t == 0) {
            if (tid < BSZ) sm.tok[tid] = 1;
        } else {
            // stage cand tables (coalesced) -> reg: val [0,8192), idx [8192,16384)
#pragma unroll
            for (int i = 0; i < 8; i++) {
                int f = i * 1024 + tid * 2;
                float2 v = aload2(cand_val + f);
                *(float2*)(sm.reg + f) = v;
                float2 u = aload2((const float*)cand_idx + f);
                *(float2*)(sm.reg + 8192 + f) = u;
            }
            __syncthreads();
            if (tid < 256) {
                int bq = tid >> 3, q = tid & 7;
                float bv = -FLT_MAX; int bi = 0x7fffffff;
                for (int gg = q; gg < FCWGS; gg += 8) {
                    float v = sm.reg[bq * 256 + gg];
                    int ix = ((const int*)sm.reg)[8192 + bq * 256 + gg];
                    if (v > bv || (v == bv && ix < bi)) { bv = v; bi = ix; }
                }
#pragma unroll
                for (int m = 1; m < 8; m <<= 1) {
                    float ov = __shfl_xor(bv, m); int oi = __shfl_xor(bi, m);
                    if (ov > bv || (ov == bv && oi < bi)) { bv = ov; bi = oi; }
                }
                if (q == 0) sm.tok[bq] = bi;
            }
        }
        __syncthreads();
        // ---- cell0 ----
        stage_h(sm.reg, h0[p]);
        __syncthreads();
        {
            const float* x0 = dec_emb + (size_t)sm.tok[b] * EDIM;
            float xv0[16], hv0[32];
#pragma unroll
            for (int i = 0; i < 4; i++) {
                float4 v = *(const float4*)(x0 + kq * 16 + i * 4);
                xv0[i*4] = v.x; xv0[i*4+1] = v.y; xv0[i*4+2] = v.z; xv0[i*4+3] = v.w;
            }
            read_slice32(sm.reg, b, kq, hv0);
            cell_compute<EDIM>(sm, sm.w0, sm.bsum0, xv0, hv0, h0[p ^ 1], c0r,
                               false, 0, j0, sm.zsh0);
        }
        gridbar(flags, sense, epoch);
        // ---- cell1 ----
        stage_h(sm.reg, h0[p ^ 1]);
        __syncthreads();
        float xv1[32], hv1[32];
        read_slice32(sm.reg, b, kq, xv1);
        __syncthreads();
        stage_h(sm.reg, h1[p]);
        __syncthreads();
        read_slice32(sm.reg, b, kq, hv1);
        cell_compute<HDIM>(sm, sm.w1, sm.bsum1, xv1, hv1, h1[p ^ 1], c1r,
                           false, 0, j0, sm.zsh1);
        gridbar(flags, sense, epoch);
        // ---- fc ----
        if (g < FCWGS)
            fc_run(sm, h1[p ^ 1], fcW, out, t, g, cand_val, cand_idx);
        if (t < TLEN - 1)
            gridbar(flags, sense, epoch);
    }
}

// ------------------------------------------------------------------- init ---
__global__ void initk(unsigned* flags)
{
    int i = blockIdx.x * 256 + threadIdx.x;
    if (i < NWG * FSTR + 16) flags[i] = 0u;
}

// ----------------------------------------------------------------- driver ---
extern "C" void kernel_launch(void* const* d_in, const int* in_sizes, int n_in,
                              void* d_out, int out_size, void* d_ws, size_t ws_size,
                              hipStream_t stream)
{
    const int*   inputs  = (const int*)d_in[0];
    const int*   lens    = (const int*)d_in[3];
    const float* enc_emb = (const float*)d_in[4];
    const float* dec_emb = (const float*)d_in[5];
    const float* W[16];
    for (int i = 0; i < 16; i++) W[i] = (const float*)d_in[6 + i];
    const float* fcW = (const float*)d_in[22];
    const float* fcb = (const float*)d_in[23];
    float* out = (float*)d_out;

    float* ws = (float*)d_ws;
    float* h0a = ws;
    float* h0b = ws + 16384;
    float* h1a = ws + 32768;
    float* h1b = ws + 49152;
    float* cand_val = ws + 65536;                       // 32*256
    int*   cand_idx = (int*)(ws + 65536 + 8192);        // 32*256
    unsigned* flags = (unsigned*)(ws + 65536 + 16384);  // 256*16 + sense

    initk<<<17, 256, 0, stream>>>(flags);
    seq2seq_persist<<<NWG, NTHR, 0, stream>>>(
        inputs, lens, enc_emb, dec_emb,
        W[0], W[1], W[2], W[3], W[4], W[5], W[6], W[7],
        W[8], W[9], W[10], W[11], W[12], W[13], W[14], W[15],
        fcW, fcb, out,
        h0a, h0b, h1a, h1b, cand_val, cand_idx, flags, flags + NWG * FSTR);
}

// Round 9
// 6494.628 us; speedup vs baseline: 1.6757x; 1.1608x over previous
//
#include <hip/hip_runtime.h>
#include <cstdint>
#include <cstddef>
#include <cfloat>

// Persistent Seq2Seq LSTM v7 (B=32,S=T=64,E=256,H=512,V=32000), fp32.
// R9 = R7 (proven: coalesced atomic staging + fence-free 2-level barrier)
//      + fcW held in VGPRs (128 floats/thread across 250 WGs = all 64MB),
//      loaded once after the encoder. Removes the 4.1GB/step fcW HBM stream
//      that R7's FETCH_SIZE identified as ~60% of all traffic.
// R8's XCD mailbox (deadlocked) is fully reverted.

#define NWG   256
#define NTHR  512
#define BSZ   32
#define SLEN  64
#define TLEN  64
#define EDIM  256
#define HDIM  512
#define VOUT  32000
#define FCWGS 250
#define FCR   128          // fc rows per WG
#define FSTR  16           // flag stride (u32)

#define XS0 20                      // EDIM slice stride
#define HSL 36                      // HDIM slice stride
#define RS0 (16 * XS0 + 16 * HSL)   // 896 floats / cell0 z-row
#define RS1 (16 * HSL + 16 * HSL)   // 1152 floats / cell1 z-row
#define HB  576                     // staged h per-b stride (16 chunks32 * 36)

struct SMem {
    float w0[8 * RS0];          // 28672 B
    float w1[8 * RS1];          // 36864 B
    float hst[32 * HB];         // 73728 B (h stage / cand stage)
    float zsh0[8 * 32];
    float zsh1[8 * 32];
    float cmv[32 * 32];         // per-rg argmax candidates
    int   cmi[32 * 32];
    float bsum0[8], bsum1[8];
    float fcb_s[FCR];
    int   tok[BSZ];
    int   llen[BSZ];
};                              // ~150 KB -> 1 WG/CU

// ------------------------------------------------- relaxed agent atomics ----
__device__ __forceinline__ float aload(const float* p) {
    return __hip_atomic_load(p, __ATOMIC_RELAXED, __HIP_MEMORY_SCOPE_AGENT);
}
__device__ __forceinline__ void astore(float* p, float v) {
    __hip_atomic_store(p, v, __ATOMIC_RELAXED, __HIP_MEMORY_SCOPE_AGENT);
}
__device__ __forceinline__ void astorei(int* p, int v) {
    __hip_atomic_store(p, v, __ATOMIC_RELAXED, __HIP_MEMORY_SCOPE_AGENT);
}
__device__ __forceinline__ float2 aload2(const float* p) {
    unsigned long long u = __hip_atomic_load((const unsigned long long*)p,
                              __ATOMIC_RELAXED, __HIP_MEMORY_SCOPE_AGENT);
    union { unsigned long long u; float2 f; } c; c.u = u; return c.f;
}

// ---------------------------------------------------------- grid barrier ----
// Two-level, fence-free (identical to R6/R7 - proven).
__device__ __forceinline__ void gridbar(unsigned* flags, unsigned* sense,
                                        unsigned& epoch)
{
    asm volatile("s_waitcnt vmcnt(0)" ::: "memory");
    __syncthreads();
    epoch++;
    const int tid = threadIdx.x;
    if (tid == 0)
        __hip_atomic_store(&flags[(size_t)blockIdx.x * FSTR], epoch,
                           __ATOMIC_RELAXED, __HIP_MEMORY_SCOPE_AGENT);
    if (blockIdx.x == 0) {
        if (tid < 64) {
#pragma unroll
            for (int k = 0; k < 4; k++) {
                const size_t idx = (size_t)(tid * 4 + k) * FSTR;
                while (__hip_atomic_load(&flags[idx], __ATOMIC_RELAXED,
                                         __HIP_MEMORY_SCOPE_AGENT) < epoch)
                    __builtin_amdgcn_s_sleep(2);
            }
        }
        __syncthreads();
        if (tid == 0)
            __hip_atomic_store(sense, epoch, __ATOMIC_RELAXED,
                               __HIP_MEMORY_SCOPE_AGENT);
    }
    if (tid == 0) {
        while (__hip_atomic_load(sense, __ATOMIC_RELAXED,
                                 __HIP_MEMORY_SCOPE_AGENT) < epoch)
            __builtin_amdgcn_s_sleep(4);
    }
    __syncthreads();
}

// ------------------------------------------------- coalesced h staging ------
// 64KB buffer hg -> LDS [b][chunk-of-32 padded to 36], b-stride 576.
__device__ __forceinline__ void stage_h(float* hst, const float* __restrict__ hg)
{
    const int t = threadIdx.x;
#pragma unroll
    for (int i = 0; i < 16; i++) {
        int f = i * 1024 + t * 2;
        float2 v = aload2(hg + f);
        int b = f >> 9, j = f & 511;
        int a = b * HB + (j >> 5) * 36 + (j & 31);
        *(float2*)(&hst[a]) = v;
    }
}
__device__ __forceinline__ void read_slice32(const float* hst, int b, int kq,
                                             float* dst)
{
#pragma unroll
    for (int i = 0; i < 8; i++) {
        float4 v = *(const float4*)(hst + b * HB + kq * 36 + i * 4);
        dst[i * 4 + 0] = v.x; dst[i * 4 + 1] = v.y;
        dst[i * 4 + 2] = v.z; dst[i * 4 + 3] = v.w;
    }
}

// ------------------------------------------------------- weight staging -----
template<int KIN>
__device__ __forceinline__ void stage_w(float* dst,
        const float* __restrict__ Wih, const float* __restrict__ Whh,
        const float* __restrict__ bih, const float* __restrict__ bhh,
        float* bsum, int j0)
{
    constexpr int XC = KIN / 16;
    constexpr int XS = (KIN == 256) ? XS0 : HSL;
    constexpr int RS = (KIN == 256) ? RS0 : RS1;
    const int tid = threadIdx.x;
    constexpr int nf4x = KIN / 4;
    for (int tt = tid; tt < 8 * nf4x; tt += NTHR) {
        int r = tt / nf4x, k = (tt % nf4x) * 4;
        int row = (r >> 1) * HDIM + j0 + (r & 1);
        float4 v = *(const float4*)(Wih + (size_t)row * KIN + k);
        *(float4*)(dst + r * RS + (k / XC) * XS + (k % XC)) = v;
    }
    for (int tt = tid; tt < 8 * 128; tt += NTHR) {
        int r = tt >> 7, k = (tt & 127) * 4;
        int row = (r >> 1) * HDIM + j0 + (r & 1);
        float4 v = *(const float4*)(Whh + (size_t)row * HDIM + k);
        *(float4*)(dst + r * RS + 16 * XS + (k >> 5) * HSL + (k & 31)) = v;
    }
    if (tid < 8) {
        int row = (tid >> 1) * HDIM + j0 + (tid & 1);
        bsum[tid] = bih[row] + bhh[row];
    }
}

// ------------------------------------------------------------- LSTM cell ----
template<int KIN>
__device__ __forceinline__ void cell_compute(SMem& sm, const float* __restrict__ w,
        const float* bsum, const float* xv, const float* hv,
        float* __restrict__ hout, float& creg, bool domask, int s, int j0,
        float* zsh)
{
    constexpr int XC = KIN / 16;
    constexpr int XS = (KIN == 256) ? XS0 : HSL;
    constexpr int RS = (KIN == 256) ? RS0 : RS1;
    const int tid = threadIdx.x;
    const int wave = tid >> 6, lane = tid & 63, kq = lane & 15, bl = lane >> 4;
    const int b = wave * 4 + bl;

#pragma unroll
    for (int r = 0; r < 8; r++) {
        float acc = 0.f;
        const float* wx = w + r * RS + kq * XS;
#pragma unroll
        for (int i = 0; i < XC / 4; i++) {
            float4 t4 = *(const float4*)(wx + i * 4);
            acc += t4.x * xv[i*4] + t4.y * xv[i*4+1] + t4.z * xv[i*4+2] + t4.w * xv[i*4+3];
        }
        const float* wh = w + r * RS + 16 * XS + kq * HSL;
#pragma unroll
        for (int i = 0; i < 8; i++) {
            float4 t4 = *(const float4*)(wh + i * 4);
            acc += t4.x * hv[i*4] + t4.y * hv[i*4+1] + t4.z * hv[i*4+2] + t4.w * hv[i*4+3];
        }
        acc += __shfl_xor(acc, 1);
        acc += __shfl_xor(acc, 2);
        acc += __shfl_xor(acc, 4);
        acc += __shfl_xor(acc, 8);
        if (kq == 0) zsh[r * 32 + b] = acc + bsum[r];
    }
    __syncthreads();
    if (tid < 64) {
        int jl = tid >> 5, bb = tid & 31;
        float zi = zsh[(0 + jl) * 32 + bb];
        float zf = zsh[(2 + jl) * 32 + bb];
        float zg = zsh[(4 + jl) * 32 + bb];
        float zo = zsh[(6 + jl) * 32 + bb];
        float iv = 1.f / (1.f + expf(-zi));
        float fv = 1.f / (1.f + expf(-zf));
        float gv = tanhf(zg);
        float ov = 1.f / (1.f + expf(-zo));
        float cold = creg;
        float c2 = fv * cold + iv * gv;
        float h2 = ov * tanhf(c2);
        int j = j0 + jl;
        if (domask) {
            bool m = s < sm.llen[bb];
            if (!m) {
                h2 = sm.hst[bb * HB + (j >> 5) * 36 + (j & 31)];  // staged hin
                c2 = cold;
            }
        }
        astore(hout + (size_t)bb * HDIM + j, h2);
        creg = c2;
    }
}

// ------------------------------------------------- fc (weights in VGPRs) ----
// tid -> (kh = tid&15: 32-float k-slice, rg = tid>>4: 4 rows of 128).
// wfc[r][i]: rows v0+rg*4+r, k = kh*32 + i*4. 16-lane shfl reduce.
__device__ __forceinline__ void fc_run(SMem& sm, const float4 (&wfc)[4][8],
        const float* __restrict__ h1g, float* __restrict__ out, int t, int g,
        float* __restrict__ cand_val, int* __restrict__ cand_idx)
{
    const int tid = threadIdx.x;
    const int kh = tid & 15, rg = tid >> 4;
    const int v0 = g * FCR;

    stage_h(sm.hst, h1g);
    __syncthreads();

    float bias[4];
#pragma unroll
    for (int r = 0; r < 4; r++) bias[r] = sm.fcb_s[rg * 4 + r];

    for (int b = 0; b < 32; b++) {
        float hv[32];
        read_slice32(sm.hst, b, kh, hv);
        float a0 = 0.f, a1 = 0.f, a2 = 0.f, a3 = 0.f;
#pragma unroll
        for (int i = 0; i < 8; i++) {
            float4 w0 = wfc[0][i], w1 = wfc[1][i], w2 = wfc[2][i], w3 = wfc[3][i];
            float h0 = hv[i*4], h1 = hv[i*4+1], h2 = hv[i*4+2], h3 = hv[i*4+3];
            a0 += w0.x * h0 + w0.y * h1 + w0.z * h2 + w0.w * h3;
            a1 += w1.x * h0 + w1.y * h1 + w1.z * h2 + w1.w * h3;
            a2 += w2.x * h0 + w2.y * h1 + w2.z * h2 + w2.w * h3;
            a3 += w3.x * h0 + w3.y * h1 + w3.z * h2 + w3.w * h3;
        }
#pragma unroll
        for (int m = 1; m < 16; m <<= 1) {
            a0 += __shfl_xor(a0, m);
            a1 += __shfl_xor(a1, m);
            a2 += __shfl_xor(a2, m);
            a3 += __shfl_xor(a3, m);
        }
        if (kh == 0) {
            float z0 = a0 + bias[0], z1 = a1 + bias[1];
            float z2 = a2 + bias[2], z3 = a3 + bias[3];
            *(float4*)(out + ((size_t)b * TLEN + t) * VOUT + v0 + rg * 4)
                = make_float4(z0, z1, z2, z3);
            float lm = z0; int li = 0;                 // ascending r: strict >
            if (z1 > lm) { lm = z1; li = 1; }
            if (z2 > lm) { lm = z2; li = 2; }
            if (z3 > lm) { lm = z3; li = 3; }
            sm.cmv[rg * 32 + b] = lm;
            sm.cmi[rg * 32 + b] = v0 + rg * 4 + li;
        }
    }
    __syncthreads();
    if (tid < 32) {        // b = tid; rg ascending = rows ascending
        float bv = sm.cmv[tid]; int bi = sm.cmi[tid];
#pragma unroll
        for (int r2 = 1; r2 < 32; r2++) {
            float v = sm.cmv[r2 * 32 + tid]; int ix = sm.cmi[r2 * 32 + tid];
            if (v > bv || (v == bv && ix < bi)) { bv = v; bi = ix; }
        }
        astore(&cand_val[(size_t)tid * NWG + g], bv);
        astorei(&cand_idx[(size_t)tid * NWG + g], bi);
    }
}

// --------------------------------------------------------- main persistent --
__global__ __launch_bounds__(NTHR, 2)
void seq2seq_persist(
    const int* __restrict__ inputs, const int* __restrict__ lens,
    const float* __restrict__ enc_emb, const float* __restrict__ dec_emb,
    const float* __restrict__ eW0ih, const float* __restrict__ eW0hh,
    const float* __restrict__ eB0ih, const float* __restrict__ eB0hh,
    const float* __restrict__ eW1ih, const float* __restrict__ eW1hh,
    const float* __restrict__ eB1ih, const float* __restrict__ eB1hh,
    const float* __restrict__ dW0ih, const float* __restrict__ dW0hh,
    const float* __restrict__ dB0ih, const float* __restrict__ dB0hh,
    const float* __restrict__ dW1ih, const float* __restrict__ dW1hh,
    const float* __restrict__ dB1ih, const float* __restrict__ dB1hh,
    const float* __restrict__ fcW, const float* __restrict__ fcb,
    float* __restrict__ out,
    float* h0a, float* h0b, float* h1a, float* h1b,
    float* cand_val, int* cand_idx, unsigned* flags, unsigned* sense)
{
    __shared__ SMem sm;
    const int g = blockIdx.x;
    const int tid = threadIdx.x;
    const int j0 = g * 2;
    unsigned epoch = 0;

    const int wave = tid >> 6, lane = tid & 63, kq16 = lane & 15, bl = lane >> 4;
    const int b = wave * 4 + bl;

    float* h0[2] = { h0a, h0b };
    float* h1[2] = { h1a, h1b };

    if (tid < 64) {
        astore(&h0a[g * 64 + tid], 0.f);
        astore(&h1a[g * 64 + tid], 0.f);
    }
    stage_w<EDIM>(sm.w0, eW0ih, eW0hh, eB0ih, eB0hh, sm.bsum0, j0);
    stage_w<HDIM>(sm.w1, eW1ih, eW1hh, eB1ih, eB1hh, sm.bsum1, j0);
    if (tid < BSZ) sm.llen[tid] = lens[tid];
    float c0r = 0.f, c1r = 0.f;
    gridbar(flags, sense, epoch);

    // ---- encoder: pipelined (cell0(s) || cell1(s-1)), 1 barrier/phase ----
    for (int s = 0; s <= SLEN; ++s) {
        int p = s & 1;
        stage_h(sm.hst, h0[p]);                 // read by cell0 (hin) + cell1 (x)
        __syncthreads();
        float xv0[16], hv0[32], xv1[32];
        if (s < SLEN) {
            int tokv = inputs[b * SLEN + s];
            const float* x0 = enc_emb + (size_t)tokv * EDIM;
#pragma unroll
            for (int i = 0; i < 4; i++) {
                float4 v = *(const float4*)(x0 + kq16 * 16 + i * 4);
                xv0[i*4] = v.x; xv0[i*4+1] = v.y; xv0[i*4+2] = v.z; xv0[i*4+3] = v.w;
            }
            read_slice32(sm.hst, b, kq16, hv0);
        }
        if (s >= 1) read_slice32(sm.hst, b, kq16, xv1);
        if (s < SLEN)
            cell_compute<EDIM>(sm, sm.w0, sm.bsum0, xv0, hv0, h0[p ^ 1], c0r,
                               true, s, j0, sm.zsh0);
        __syncthreads();
        if (s >= 1) {
            int q = (s - 1) & 1;
            stage_h(sm.hst, h1[q]);
            __syncthreads();
            float hv1[32];
            read_slice32(sm.hst, b, kq16, hv1);
            cell_compute<HDIM>(sm, sm.w1, sm.bsum1, xv1, hv1, h1[q ^ 1], c1r,
                               true, s - 1, j0, sm.zsh1);
        }
        gridbar(flags, sense, epoch);
    }
    // encoder finals in h0[0], h1[0]

    // ---- decoder setup: stage dec weights + load fcW into registers ----
    stage_w<EDIM>(sm.w0, dW0ih, dW0hh, dB0ih, dB0hh, sm.bsum0, j0);
    stage_w<HDIM>(sm.w1, dW1ih, dW1hh, dB1ih, dB1hh, sm.bsum1, j0);
    float4 wfc[4][8];
    {
        const int kh = tid & 15, rg = tid >> 4;
        if (g < FCWGS) {
            const float* wp = fcW + ((size_t)g * FCR + rg * 4) * HDIM + kh * 32;
#pragma unroll
            for (int r = 0; r < 4; r++)
#pragma unroll
                for (int i = 0; i < 8; i++)
                    wfc[r][i] = *(const float4*)(wp + (size_t)r * HDIM + i * 4);
            for (int i = tid; i < FCR; i += NTHR) sm.fcb_s[i] = fcb[g * FCR + i];
        }
    }
    c0r = 0.f; c1r = 0.f;
    __syncthreads();

    // ---- decoder: 3 barriers/step ----
    for (int t = 0; t < TLEN; ++t) {
        int p = t & 1;
        if (t == 0) {
            if (tid < BSZ) sm.tok[tid] = 1;
        } else {
            // stage cand tables (coalesced) -> hst: val [0,8192), idx [8192,16384)
#pragma unroll
            for (int i = 0; i < 8; i++) {
                int f = i * 1024 + tid * 2;
                float2 v = aload2(cand_val + f);
                *(float2*)(sm.hst + f) = v;
                float2 u = aload2((const float*)cand_idx + f);
                *(float2*)(sm.hst + 8192 + f) = u;
            }
            __syncthreads();
            if (tid < 256) {
                int bq = tid >> 3, q = tid & 7;
                float bv = -FLT_MAX; int bi = 0x7fffffff;
                for (int gg = q; gg < FCWGS; gg += 8) {
                    float v = sm.hst[bq * 256 + gg];
                    int ix = ((const int*)sm.hst)[8192 + bq * 256 + gg];
                    if (v > bv || (v == bv && ix < bi)) { bv = v; bi = ix; }
                }
#pragma unroll
                for (int m = 1; m < 8; m <<= 1) {
                    float ov = __shfl_xor(bv, m); int oi = __shfl_xor(bi, m);
                    if (ov > bv || (ov == bv && oi < bi)) { bv = ov; bi = oi; }
                }
                if (q == 0) sm.tok[bq] = bi;
            }
        }
        __syncthreads();
        // ---- cell0 ----
        stage_h(sm.hst, h0[p]);
        __syncthreads();
        {
            const float* x0 = dec_emb + (size_t)sm.tok[b] * EDIM;
            float xv0[16], hv0[32];
#pragma unroll
            for (int i = 0; i < 4; i++) {
                float4 v = *(const float4*)(x0 + kq16 * 16 + i * 4);
                xv0[i*4] = v.x; xv0[i*4+1] = v.y; xv0[i*4+2] = v.z; xv0[i*4+3] = v.w;
            }
            read_slice32(sm.hst, b, kq16, hv0);
            cell_compute<EDIM>(sm, sm.w0, sm.bsum0, xv0, hv0, h0[p ^ 1], c0r,
                               false, 0, j0, sm.zsh0);
        }
        gridbar(flags, sense, epoch);
        // ---- cell1 ----
        stage_h(sm.hst, h0[p ^ 1]);
        __syncthreads();
        float xv1[32];
        read_slice32(sm.hst, b, kq16, xv1);
        __syncthreads();
        stage_h(sm.hst, h1[p]);
        __syncthreads();
        {
            float hv1[32];
            read_slice32(sm.hst, b, kq16, hv1);
            cell_compute<HDIM>(sm, sm.w1, sm.bsum1, xv1, hv1, h1[p ^ 1], c1r,
                               false, 0, j0, sm.zsh1);
        }
        gridbar(flags, sense, epoch);
        // ---- fc (W in VGPRs; only h1' staging + pure VALU) ----
        if (g < FCWGS)
            fc_run(sm, wfc, h1[p ^ 1], out, t, g, cand_val, cand_idx);
        if (t < TLEN - 1)
            gridbar(flags, sense, epoch);
    }
}

// ------------------------------------------------------------------- init ---
__global__ void initk(unsigned* flags)
{
    int i = blockIdx.x * 256 + threadIdx.x;
    if (i < NWG * FSTR + 16) flags[i] = 0u;
}

// ----------------------------------------------------------------- driver ---
extern "C" void kernel_launch(void* const* d_in, const int* in_sizes, int n_in,
                              void* d_out, int out_size, void* d_ws, size_t ws_size,
                              hipStream_t stream)
{
    const int*   inputs  = (const int*)d_in[0];
    const int*   lens    = (const int*)d_in[3];
    const float* enc_emb = (const float*)d_in[4];
    const float* dec_emb = (const float*)d_in[5];
    const float* W[16];
    for (int i = 0; i < 16; i++) W[i] = (const float*)d_in[6 + i];
    const float* fcW = (const float*)d_in[22];
    const float* fcb = (const float*)d_in[23];
    float* out = (float*)d_out;

    float* ws = (float*)d_ws;
    float* h0a = ws;
    float* h0b = ws + 16384;
    float* h1a = ws + 32768;
    float* h1b = ws + 49152;
    float* cand_val = ws + 65536;                       // 32*256
    int*   cand_idx = (int*)(ws + 65536 + 8192);        // 32*256
    unsigned* flags = (unsigned*)(ws + 65536 + 16384);  // 256*16 + sense

    initk<<<17, 256, 0, stream>>>(flags);
    seq2seq_persist<<<NWG, NTHR, 0, stream>>>(
        inputs, lens, enc_emb, dec_emb,
        W[0], W[1], W[2], W[3], W[4], W[5], W[6], W[7],
        W[8], W[9], W[10], W[11], W[12], W[13], W[14], W[15],
        fcW, fcb, out,
        h0a, h0b, h1a, h1b, cand_val, cand_idx, flags, flags + NWG * FSTR);
}

// Round 10
// 4732.221 us; speedup vs baseline: 2.2998x; 1.3724x over previous
//
#include <hip/hip_runtime.h>
#include <cstdint>
#include <cstddef>
#include <cfloat>

// Persistent Seq2Seq LSTM v8 (B=32,S=T=64,E=256,H=512,V=32000), fp32.
// R10: consumer staging via PLAIN CACHED loads (L2-amplified broadcast):
//   - producers keep relaxed agent-atomic stores (LLC, proven R5-R9)
//   - every h generation / cand table gets a FRESH address (no stale line
//     possible within a run); one agent-acquire fence at kernel entry
//     (buffer_inv) kills lines retained across graph replays
//   - per stage event: 8 XCD L2 fills x 64KB instead of 256 WG x 64KB atomic
//     reads (32x less cross-fabric traffic)
//   - ws_size < 21.2MB -> fallback flag = R9 behavior (ping-pong + atomic)
// fcW stays in VGPRs (R9). Barrier, cell math, fc unchanged (R6-R9 proven).

#define NWG   256
#define NTHR  512
#define BSZ   32
#define SLEN  64
#define TLEN  64
#define EDIM  256
#define HDIM  512
#define VOUT  32000
#define FCWGS 250
#define FCR   128
#define FSTR  16

#define XS0 20
#define HSL 36
#define RS0 (16 * XS0 + 16 * HSL)
#define RS1 (16 * HSL + 16 * HSL)
#define HB  576
#define HGEN 16384          // floats per h generation (64KB)
#define NHG_FRESH 258
#define NHG_FB    8
#define NCG_FRESH 64
#define NCG_FB    2

struct SMem {
    float w0[8 * RS0];
    float w1[8 * RS1];
    float hst[32 * HB];
    float zsh0[8 * 32];
    float zsh1[8 * 32];
    float cmv[32 * 32];
    int   cmi[32 * 32];
    float bsum0[8], bsum1[8];
    float fcb_s[FCR];
    int   tok[BSZ];
    int   llen[BSZ];
};

// ------------------------------------------------- relaxed agent atomics ----
__device__ __forceinline__ void astore(float* p, float v) {
    __hip_atomic_store(p, v, __ATOMIC_RELAXED, __HIP_MEMORY_SCOPE_AGENT);
}
__device__ __forceinline__ void astorei(int* p, int v) {
    __hip_atomic_store(p, v, __ATOMIC_RELAXED, __HIP_MEMORY_SCOPE_AGENT);
}
__device__ __forceinline__ float2 aload2(const float* p) {
    unsigned long long u = __hip_atomic_load((const unsigned long long*)p,
                              __ATOMIC_RELAXED, __HIP_MEMORY_SCOPE_AGENT);
    union { unsigned long long u; float2 f; } c; c.u = u; return c.f;
}

// -------------------------------------------------- buffer generation map ---
// fresh: gen index g used directly. fallback: 8-buffer ping-pong preserving
// the enc-final -> dec-initial aliasing (g64 -> buf0, g129 -> buf2).
__device__ __forceinline__ int fbmap(int g) {
    if (g < 65)  return (g & 1);
    if (g < 130) return 2 + ((g - 65) & 1);
    if (g < 194) return 4 + ((g - 130) & 1);
    return 6 + ((g - 194) & 1);
}
__device__ __forceinline__ float* genp(float* hb, int g, int fresh) {
    return hb + (size_t)(fresh ? g : fbmap(g)) * HGEN;
}

// ---------------------------------------------------------- grid barrier ----
// Two-level, fence-free (identical to R6-R9, proven).
__device__ __forceinline__ void gridbar(unsigned* flags, unsigned* sense,
                                        unsigned& epoch)
{
    asm volatile("s_waitcnt vmcnt(0)" ::: "memory");
    __syncthreads();
    epoch++;
    const int tid = threadIdx.x;
    if (tid == 0)
        __hip_atomic_store(&flags[(size_t)blockIdx.x * FSTR], epoch,
                           __ATOMIC_RELAXED, __HIP_MEMORY_SCOPE_AGENT);
    if (blockIdx.x == 0) {
        if (tid < 64) {
#pragma unroll
            for (int k = 0; k < 4; k++) {
                const size_t idx = (size_t)(tid * 4 + k) * FSTR;
                while (__hip_atomic_load(&flags[idx], __ATOMIC_RELAXED,
                                         __HIP_MEMORY_SCOPE_AGENT) < epoch)
                    __builtin_amdgcn_s_sleep(2);
            }
        }
        __syncthreads();
        if (tid == 0)
            __hip_atomic_store(sense, epoch, __ATOMIC_RELAXED,
                               __HIP_MEMORY_SCOPE_AGENT);
    }
    if (tid == 0) {
        while (__hip_atomic_load(sense, __ATOMIC_RELAXED,
                                 __HIP_MEMORY_SCOPE_AGENT) < epoch)
            __builtin_amdgcn_s_sleep(4);
    }
    __syncthreads();
}

// ------------------------------------------------- h staging (dual path) ----
// cached: plain float4 loads (L2-amplified; fresh addresses only).
// atomic: R9 path (fallback when ws too small for fresh buffers).
__device__ __forceinline__ void stage_h(float* hst, const float* __restrict__ hg,
                                        int cached)
{
    const int t = threadIdx.x;
    if (cached) {
#pragma unroll
        for (int i = 0; i < 8; i++) {
            int f = i * 2048 + t * 4;
            float4 v = *(const float4*)(hg + f);
            int b = f >> 9, j = f & 511;
            *(float4*)(&hst[b * HB + (j >> 5) * 36 + (j & 31)]) = v;
        }
    } else {
#pragma unroll
        for (int i = 0; i < 16; i++) {
            int f = i * 1024 + t * 2;
            float2 v = aload2(hg + f);
            int b = f >> 9, j = f & 511;
            *(float2*)(&hst[b * HB + (j >> 5) * 36 + (j & 31)]) = v;
        }
    }
}
__device__ __forceinline__ void read_slice32(const float* hst, int b, int kq,
                                             float* dst)
{
#pragma unroll
    for (int i = 0; i < 8; i++) {
        float4 v = *(const float4*)(hst + b * HB + kq * 36 + i * 4);
        dst[i * 4 + 0] = v.x; dst[i * 4 + 1] = v.y;
        dst[i * 4 + 2] = v.z; dst[i * 4 + 3] = v.w;
    }
}

// ------------------------------------------------------- weight staging -----
template<int KIN>
__device__ __forceinline__ void stage_w(float* dst,
        const float* __restrict__ Wih, const float* __restrict__ Whh,
        const float* __restrict__ bih, const float* __restrict__ bhh,
        float* bsum, int j0)
{
    constexpr int XC = KIN / 16;
    constexpr int XS = (KIN == 256) ? XS0 : HSL;
    constexpr int RS = (KIN == 256) ? RS0 : RS1;
    const int tid = threadIdx.x;
    constexpr int nf4x = KIN / 4;
    for (int tt = tid; tt < 8 * nf4x; tt += NTHR) {
        int r = tt / nf4x, k = (tt % nf4x) * 4;
        int row = (r >> 1) * HDIM + j0 + (r & 1);
        float4 v = *(const float4*)(Wih + (size_t)row * KIN + k);
        *(float4*)(dst + r * RS + (k / XC) * XS + (k % XC)) = v;
    }
    for (int tt = tid; tt < 8 * 128; tt += NTHR) {
        int r = tt >> 7, k = (tt & 127) * 4;
        int row = (r >> 1) * HDIM + j0 + (r & 1);
        float4 v = *(const float4*)(Whh + (size_t)row * HDIM + k);
        *(float4*)(dst + r * RS + 16 * XS + (k >> 5) * HSL + (k & 31)) = v;
    }
    if (tid < 8) {
        int row = (tid >> 1) * HDIM + j0 + (tid & 1);
        bsum[tid] = bih[row] + bhh[row];
    }
}

// ------------------------------------------------------------- LSTM cell ----
template<int KIN>
__device__ __forceinline__ void cell_compute(SMem& sm, const float* __restrict__ w,
        const float* bsum, const float* xv, const float* hv,
        float* __restrict__ hout, float& creg, bool domask, int s, int j0,
        float* zsh)
{
    constexpr int XC = KIN / 16;
    constexpr int XS = (KIN == 256) ? XS0 : HSL;
    constexpr int RS = (KIN == 256) ? RS0 : RS1;
    const int tid = threadIdx.x;
    const int wave = tid >> 6, lane = tid & 63, kq = lane & 15, bl = lane >> 4;
    const int b = wave * 4 + bl;

#pragma unroll
    for (int r = 0; r < 8; r++) {
        float acc = 0.f;
        const float* wx = w + r * RS + kq * XS;
#pragma unroll
        for (int i = 0; i < XC / 4; i++) {
            float4 t4 = *(const float4*)(wx + i * 4);
            acc += t4.x * xv[i*4] + t4.y * xv[i*4+1] + t4.z * xv[i*4+2] + t4.w * xv[i*4+3];
        }
        const float* wh = w + r * RS + 16 * XS + kq * HSL;
#pragma unroll
        for (int i = 0; i < 8; i++) {
            float4 t4 = *(const float4*)(wh + i * 4);
            acc += t4.x * hv[i*4] + t4.y * hv[i*4+1] + t4.z * hv[i*4+2] + t4.w * hv[i*4+3];
        }
        acc += __shfl_xor(acc, 1);
        acc += __shfl_xor(acc, 2);
        acc += __shfl_xor(acc, 4);
        acc += __shfl_xor(acc, 8);
        if (kq == 0) zsh[r * 32 + b] = acc + bsum[r];
    }
    __syncthreads();
    if (tid < 64) {
        int jl = tid >> 5, bb = tid & 31;
        float zi = zsh[(0 + jl) * 32 + bb];
        float zf = zsh[(2 + jl) * 32 + bb];
        float zg = zsh[(4 + jl) * 32 + bb];
        float zo = zsh[(6 + jl) * 32 + bb];
        float iv = 1.f / (1.f + expf(-zi));
        float fv = 1.f / (1.f + expf(-zf));
        float gv = tanhf(zg);
        float ov = 1.f / (1.f + expf(-zo));
        float cold = creg;
        float c2 = fv * cold + iv * gv;
        float h2 = ov * tanhf(c2);
        int j = j0 + jl;
        if (domask) {
            bool m = s < sm.llen[bb];
            if (!m) {
                h2 = sm.hst[bb * HB + (j >> 5) * 36 + (j & 31)];  // staged hin
                c2 = cold;
            }
        }
        astore(hout + (size_t)bb * HDIM + j, h2);
        creg = c2;
    }
}

// ------------------------------------------------- fc (weights in VGPRs) ----
__device__ __forceinline__ void fc_run(SMem& sm, const float4 (&wfc)[4][8],
        const float* __restrict__ h1g, float* __restrict__ out, int t, int g,
        float* __restrict__ cand_val, int* __restrict__ cand_idx, int cached)
{
    const int tid = threadIdx.x;
    const int kh = tid & 15, rg = tid >> 4;
    const int v0 = g * FCR;

    stage_h(sm.hst, h1g, cached);
    __syncthreads();

    float bias[4];
#pragma unroll
    for (int r = 0; r < 4; r++) bias[r] = sm.fcb_s[rg * 4 + r];

    for (int b = 0; b < 32; b++) {
        float hv[32];
        read_slice32(sm.hst, b, kh, hv);
        float a0 = 0.f, a1 = 0.f, a2 = 0.f, a3 = 0.f;
#pragma unroll
        for (int i = 0; i < 8; i++) {
            float4 w0 = wfc[0][i], w1 = wfc[1][i], w2 = wfc[2][i], w3 = wfc[3][i];
            float h0 = hv[i*4], h1 = hv[i*4+1], h2 = hv[i*4+2], h3 = hv[i*4+3];
            a0 += w0.x * h0 + w0.y * h1 + w0.z * h2 + w0.w * h3;
            a1 += w1.x * h0 + w1.y * h1 + w1.z * h2 + w1.w * h3;
            a2 += w2.x * h0 + w2.y * h1 + w2.z * h2 + w2.w * h3;
            a3 += w3.x * h0 + w3.y * h1 + w3.z * h2 + w3.w * h3;
        }
#pragma unroll
        for (int m = 1; m < 16; m <<= 1) {
            a0 += __shfl_xor(a0, m);
            a1 += __shfl_xor(a1, m);
            a2 += __shfl_xor(a2, m);
            a3 += __shfl_xor(a3, m);
        }
        if (kh == 0) {
            float z0 = a0 + bias[0], z1 = a1 + bias[1];
            float z2 = a2 + bias[2], z3 = a3 + bias[3];
            *(float4*)(out + ((size_t)b * TLEN + t) * VOUT + v0 + rg * 4)
                = make_float4(z0, z1, z2, z3);
            float lm = z0; int li = 0;                 // ascending r: strict >
            if (z1 > lm) { lm = z1; li = 1; }
            if (z2 > lm) { lm = z2; li = 2; }
            if (z3 > lm) { lm = z3; li = 3; }
            sm.cmv[rg * 32 + b] = lm;
            sm.cmi[rg * 32 + b] = v0 + rg * 4 + li;
        }
    }
    __syncthreads();
    if (tid < 32) {
        float bv = sm.cmv[tid]; int bi = sm.cmi[tid];
#pragma unroll
        for (int r2 = 1; r2 < 32; r2++) {
            float v = sm.cmv[r2 * 32 + tid]; int ix = sm.cmi[r2 * 32 + tid];
            if (v > bv || (v == bv && ix < bi)) { bv = v; bi = ix; }
        }
        astore(&cand_val[(size_t)tid * NWG + g], bv);
        astorei(&cand_idx[(size_t)tid * NWG + g], bi);
    }
}

// --------------------------------------------------------- main persistent --
__global__ __launch_bounds__(NTHR, 2)
void seq2seq_persist(
    const int* __restrict__ inputs, const int* __restrict__ lens,
    const float* __restrict__ enc_emb, const float* __restrict__ dec_emb,
    const float* __restrict__ eW0ih, const float* __restrict__ eW0hh,
    const float* __restrict__ eB0ih, const float* __restrict__ eB0hh,
    const float* __restrict__ eW1ih, const float* __restrict__ eW1hh,
    const float* __restrict__ eB1ih, const float* __restrict__ eB1hh,
    const float* __restrict__ dW0ih, const float* __restrict__ dW0hh,
    const float* __restrict__ dB0ih, const float* __restrict__ dB0hh,
    const float* __restrict__ dW1ih, const float* __restrict__ dW1hh,
    const float* __restrict__ dB1ih, const float* __restrict__ dB1hh,
    const float* __restrict__ fcW, const float* __restrict__ fcb,
    float* __restrict__ out,
    float* hb, float* cb, unsigned* flags, unsigned* sense, int fresh)
{
    __shared__ SMem sm;
    const int g = blockIdx.x;
    const int tid = threadIdx.x;
    const int j0 = g * 2;
    unsigned epoch = 0;

    // entry: invalidate L1/L2 lines retained from a previous graph replay
    __builtin_amdgcn_fence(__ATOMIC_ACQUIRE, "agent");

    const int wave = tid >> 6, lane = tid & 63, kq16 = lane & 15, bl = lane >> 4;
    const int b = wave * 4 + bl;

    if (tid < 64) {
        astore(&genp(hb, 0, fresh)[g * 64 + tid], 0.f);    // h0e[0]
        astore(&genp(hb, 65, fresh)[g * 64 + tid], 0.f);   // h1e[0]
    }
    stage_w<EDIM>(sm.w0, eW0ih, eW0hh, eB0ih, eB0hh, sm.bsum0, j0);
    stage_w<HDIM>(sm.w1, eW1ih, eW1hh, eB1ih, eB1hh, sm.bsum1, j0);
    if (tid < BSZ) sm.llen[tid] = lens[tid];
    float c0r = 0.f, c1r = 0.f;
    gridbar(flags, sense, epoch);

    // ---- encoder: pipelined (cell0(s) || cell1(s-1)), 1 barrier/phase ----
    // gens: h0e[k]=k (0..64), h1e[k]=65+k (65..129)
    for (int s = 0; s <= SLEN; ++s) {
        stage_h(sm.hst, genp(hb, s, fresh), fresh);
        __syncthreads();
        float xv0[16], hv0[32], xv1[32];
        if (s < SLEN) {
            int tokv = inputs[b * SLEN + s];
            const float* x0 = enc_emb + (size_t)tokv * EDIM;
#pragma unroll
            for (int i = 0; i < 4; i++) {
                float4 v = *(const float4*)(x0 + kq16 * 16 + i * 4);
                xv0[i*4] = v.x; xv0[i*4+1] = v.y; xv0[i*4+2] = v.z; xv0[i*4+3] = v.w;
            }
            read_slice32(sm.hst, b, kq16, hv0);
        }
        if (s >= 1) read_slice32(sm.hst, b, kq16, xv1);
        if (s < SLEN)
            cell_compute<EDIM>(sm, sm.w0, sm.bsum0, xv0, hv0,
                               genp(hb, s + 1, fresh), c0r, true, s, j0, sm.zsh0);
        __syncthreads();
        if (s >= 1) {
            stage_h(sm.hst, genp(hb, 65 + s - 1, fresh), fresh);
            __syncthreads();
            float hv1[32];
            read_slice32(sm.hst, b, kq16, hv1);
            cell_compute<HDIM>(sm, sm.w1, sm.bsum1, xv1, hv1,
                               genp(hb, 65 + s, fresh), c1r, true, s - 1, j0, sm.zsh1);
        }
        gridbar(flags, sense, epoch);
    }
    // encoder finals: h0e[64] = gen 64, h1e[64] = gen 129

    // ---- decoder setup: stage dec weights + load fcW into registers ----
    stage_w<EDIM>(sm.w0, dW0ih, dW0hh, dB0ih, dB0hh, sm.bsum0, j0);
    stage_w<HDIM>(sm.w1, dW1ih, dW1hh, dB1ih, dB1hh, sm.bsum1, j0);
    float4 wfc[4][8];
    {
        const int kh = tid & 15, rg = tid >> 4;
        if (g < FCWGS) {
            const float* wp = fcW + ((size_t)g * FCR + rg * 4) * HDIM + kh * 32;
#pragma unroll
            for (int r = 0; r < 4; r++)
#pragma unroll
                for (int i = 0; i < 8; i++)
                    wfc[r][i] = *(const float4*)(wp + (size_t)r * HDIM + i * 4);
            for (int i = tid; i < FCR; i += NTHR) sm.fcb_s[i] = fcb[g * FCR + i];
        }
    }
    c0r = 0.f; c1r = 0.f;
    __syncthreads();

    // gens: h0d[k] = (k==0 ? 64 : 129+k), h1d[k] = (k==0 ? 129 : 193+k)
    for (int t = 0; t < TLEN; ++t) {
        if (t == 0) {
            if (tid < BSZ) sm.tok[tid] = 1;
        } else {
            const float* cvp = cb + (size_t)(fresh ? (t - 1) : ((t - 1) & 1)) * HGEN;
            const float* cip = cvp + 8192;
            if (fresh) {
#pragma unroll
                for (int i = 0; i < 4; i++) {
                    int f = i * 2048 + tid * 4;
                    *(float4*)(sm.hst + f) = *(const float4*)(cvp + f);
                    *(float4*)(sm.hst + 8192 + f) = *(const float4*)(cip + f);
                }
            } else {
#pragma unroll
                for (int i = 0; i < 8; i++) {
                    int f = i * 1024 + tid * 2;
                    *(float2*)(sm.hst + f) = aload2(cvp + f);
                    *(float2*)(sm.hst + 8192 + f) = aload2(cip + f);
                }
            }
            __syncthreads();
            if (tid < 256) {
                int bq = tid >> 3, q = tid & 7;
                float bv = -FLT_MAX; int bi = 0x7fffffff;
                for (int gg = q; gg < FCWGS; gg += 8) {
                    float v = sm.hst[bq * 256 + gg];
                    int ix = ((const int*)sm.hst)[8192 + bq * 256 + gg];
                    if (v > bv || (v == bv && ix < bi)) { bv = v; bi = ix; }
                }
#pragma unroll
                for (int m = 1; m < 8; m <<= 1) {
                    float ov = __shfl_xor(bv, m); int oi = __shfl_xor(bi, m);
                    if (ov > bv || (ov == bv && oi < bi)) { bv = ov; bi = oi; }
                }
                if (q == 0) sm.tok[bq] = bi;
            }
        }
        __syncthreads();
        const int g0i = (t == 0) ? 64 : 129 + t;
        const int g0o = 129 + t + 1;
        const int g1i = (t == 0) ? 129 : 193 + t;
        const int g1o = 193 + t + 1;
        // ---- cell0 ----
        stage_h(sm.hst, genp(hb, g0i, fresh), fresh);
        __syncthreads();
        {
            const float* x0 = dec_emb + (size_t)sm.tok[b] * EDIM;
            float xv0[16], hv0[32];
#pragma unroll
            for (int i = 0; i < 4; i++) {
                float4 v = *(const float4*)(x0 + kq16 * 16 + i * 4);
                xv0[i*4] = v.x; xv0[i*4+1] = v.y; xv0[i*4+2] = v.z; xv0[i*4+3] = v.w;
            }
            read_slice32(sm.hst, b, kq16, hv0);
            cell_compute<EDIM>(sm, sm.w0, sm.bsum0, xv0, hv0,
                               genp(hb, g0o, fresh), c0r, false, 0, j0, sm.zsh0);
        }
        gridbar(flags, sense, epoch);
        // ---- cell1 ----
        stage_h(sm.hst, genp(hb, g0o, fresh), fresh);
        __syncthreads();
        float xv1[32];
        read_slice32(sm.hst, b, kq16, xv1);
        __syncthreads();
        stage_h(sm.hst, genp(hb, g1i, fresh), fresh);
        __syncthreads();
        {
            float hv1[32];
            read_slice32(sm.hst, b, kq16, hv1);
            cell_compute<HDIM>(sm, sm.w1, sm.bsum1, xv1, hv1,
                               genp(hb, g1o, fresh), c1r, false, 0, j0, sm.zsh1);
        }
        gridbar(flags, sense, epoch);
        // ---- fc ----
        if (g < FCWGS) {
            float* cvt = cb + (size_t)(fresh ? t : (t & 1)) * HGEN;
            fc_run(sm, wfc, genp(hb, g1o, fresh), out, t, g,
                   cvt, (int*)(cvt + 8192), fresh);
        }
        if (t < TLEN - 1)
            gridbar(flags, sense, epoch);
    }
}

// ------------------------------------------------------------------- init ---
__global__ void initk(unsigned* flags)
{
    int i = blockIdx.x * 256 + threadIdx.x;
    if (i < NWG * FSTR + 16) flags[i] = 0u;
}

// ----------------------------------------------------------------- driver ---
extern "C" void kernel_launch(void* const* d_in, const int* in_sizes, int n_in,
                              void* d_out, int out_size, void* d_ws, size_t ws_size,
                              hipStream_t stream)
{
    const int*   inputs  = (const int*)d_in[0];
    const int*   lens    = (const int*)d_in[3];
    const float* enc_emb = (const float*)d_in[4];
    const float* dec_emb = (const float*)d_in[5];
    const float* W[16];
    for (int i = 0; i < 16; i++) W[i] = (const float*)d_in[6 + i];
    const float* fcW = (const float*)d_in[22];
    const float* fcb = (const float*)d_in[23];
    float* out = (float*)d_out;

    float* ws = (float*)d_ws;
    unsigned* flags = (unsigned*)ws;                   // 256*16 + sense line
    float* hb = ws + 8192;                             // h generations
    // fresh layout: 258 h gens + 64 cand gens; fallback: 8 + 2
    size_t needB = (size_t)(8192 + (NHG_FRESH + NCG_FRESH) * HGEN) * 4;
    int fresh = (ws_size >= needB) ? 1 : 0;
    float* cb = hb + (size_t)(fresh ? NHG_FRESH : NHG_FB) * HGEN;

    initk<<<17, 256, 0, stream>>>(flags);
    seq2seq_persist<<<NWG, NTHR, 0, stream>>>(
        inputs, lens, enc_emb, dec_emb,
        W[0], W[1], W[2], W[3], W[4], W[5], W[6], W[7],
        W[8], W[9], W[10], W[11], W[12], W[13], W[14], W[15],
        fcW, fcb, out,
        hb, cb, flags, flags + NWG * FSTR, fresh);
}